// Round 1
// baseline (386.005 us; speedup 1.0000x reference)
//
#include <hip/hip_runtime.h>
#include <hip/hip_bf16.h>
#include <math.h>

// Problem constants (fixed by setup_inputs)
#define S_LEN 4096
#define D_HID 512
#define P_DIM 512
#define H_NUM 8
#define DH 64
#define CHUNK 64
#define NC (S_LEN / CHUNK)   // 64 chunks per head
#define EPS 1e-6f

// ---------------------------------------------------------------------------
// GEMM: out = A[M,K] @ W[K,N] (+bias) (optional elu+1 activation)
// SPLIT=1 writes head-split layout out[h][m][d] with h=n/64, d=n%64
// ---------------------------------------------------------------------------
template<int ACT, int SPLIT>
__global__ __launch_bounds__(256) void gemm_kernel(
    const float* __restrict__ A, const float* __restrict__ W,
    const float* __restrict__ bias, float* __restrict__ out,
    int M, int N, int K) {
  __shared__ float As[16][65];   // [BK][BM+1]
  __shared__ float Bs[16][65];   // [BK][BN+1]
  int bm = blockIdx.x * 64;
  int bn = blockIdx.y * 64;
  int tid = threadIdx.x;
  int tr = tid >> 4, tc = tid & 15;
  float acc[4][4] = {};
  for (int k0 = 0; k0 < K; k0 += 16) {
#pragma unroll
    for (int i = 0; i < 4; i++) {
      int e = tid + 256 * i;           // 0..1023
      int r = e >> 4;                  // 0..63 (row within tile)
      int cc = e & 15;                 // 0..15 (k within tile)
      As[cc][r] = A[(size_t)(bm + r) * K + k0 + cc];
    }
#pragma unroll
    for (int i = 0; i < 4; i++) {
      int e = tid + 256 * i;
      int r = e >> 6;                  // 0..15 (k)
      int cc = e & 63;                 // 0..63 (n)
      Bs[r][cc] = W[(size_t)(k0 + r) * N + bn + cc];
    }
    __syncthreads();
#pragma unroll
    for (int kk = 0; kk < 16; kk++) {
      float a[4], b[4];
#pragma unroll
      for (int i = 0; i < 4; i++) a[i] = As[kk][tr * 4 + i];
#pragma unroll
      for (int j = 0; j < 4; j++) b[j] = Bs[kk][tc * 4 + j];
#pragma unroll
      for (int i = 0; i < 4; i++)
#pragma unroll
        for (int j = 0; j < 4; j++) acc[i][j] += a[i] * b[j];
    }
    __syncthreads();
  }
#pragma unroll
  for (int i = 0; i < 4; i++) {
    int m = bm + tr * 4 + i;
#pragma unroll
    for (int j = 0; j < 4; j++) {
      int n = bn + tc * 4 + j;
      float val = acc[i][j];
      if (bias) val += bias[n];
      if (ACT) val = (val > 0.f) ? (val + 1.f) : expf(val);  // elu(x)+1
      if (SPLIT)
        out[(size_t)(n >> 6) * M * 64 + (size_t)m * 64 + (n & 63)] = val;
      else
        out[(size_t)m * N + n] = val;
    }
  }
}

// ---------------------------------------------------------------------------
// Per-(head,chunk) KV outer-product sum and k sum.
// KV[h][c][d][e] = sum_t sk[t][d]*v[t][e] ; ksum[h][c][d] = sum_t sk[t][d]
// ---------------------------------------------------------------------------
__global__ __launch_bounds__(256) void chunk_sum_kernel(
    const float* __restrict__ sk_g, const float* __restrict__ v_g,
    float* __restrict__ KV, float* __restrict__ ksum) {
  __shared__ float sk_s[64][65], v_s[64][65];
  int h = blockIdx.x / NC, c = blockIdx.x % NC;
  int tid = threadIdx.x;
  size_t base = (size_t)h * S_LEN * DH + (size_t)c * CHUNK * DH;
#pragma unroll
  for (int i = 0; i < 16; i++) {
    int e = i * 256 + tid;
    int t = e >> 6, d = e & 63;
    sk_s[t][d] = sk_g[base + e];
    v_s[t][d] = v_g[base + e];
  }
  __syncthreads();
  int e = tid & 63, db = (tid >> 6) * 16;
  float acc[16] = {};
  for (int t = 0; t < 64; t++) {
    float ve = v_s[t][e];
#pragma unroll
    for (int i = 0; i < 16; i++) acc[i] += sk_s[t][db + i] * ve;
  }
  float* outp = KV + (size_t)(h * NC + c) * (DH * DH);
#pragma unroll
  for (int i = 0; i < 16; i++) outp[(db + i) * 64 + e] = acc[i];
  if (tid < 64) {
    float s = 0.f;
    for (int t = 0; t < 64; t++) s += sk_s[t][tid];
    ksum[(h * NC + c) * DH + tid] = s;
  }
}

// ---------------------------------------------------------------------------
// In-place exclusive prefix over chunks, seeded by persistent memory.
// grid = H*16 blocks; block b handles entries [g*256 + tid] of the 64x64.
// ---------------------------------------------------------------------------
__global__ __launch_bounds__(256) void prefix_kernel(
    float* __restrict__ KV, float* __restrict__ ksum,
    const float* __restrict__ M_mem, const float* __restrict__ z_mem) {
  int h = blockIdx.x >> 4, g = blockIdx.x & 15;
  int tid = threadIdx.x;
  int entry = g * 256 + tid;   // 0..4095
  float pref = M_mem[h * (DH * DH) + entry];
  for (int c = 0; c < NC; c++) {
    float* p = KV + (size_t)(h * NC + c) * (DH * DH) + entry;
    float val = *p;
    *p = pref;
    pref += val;
  }
  if (g == 0 && tid < 64) {
    float zp = z_mem[h * DH + tid];
    for (int c = 0; c < NC; c++) {
      float* p = ksum + (h * NC + c) * DH + tid;
      float val = *p;
      *p = zp;
      zp += val;
    }
  }
}

// ---------------------------------------------------------------------------
// Per-(head,chunk) output: inter part via M_prefix, intra causal part.
// attn[s][h*64+e] = (sq·Mpref + tril(sq·skT)·v) / (sq·zpref + rowsum + eps)
// ---------------------------------------------------------------------------
__global__ __launch_bounds__(256) void attn_chunk_kernel(
    const float* __restrict__ sq_g, const float* __restrict__ sk_g,
    const float* __restrict__ v_g, const float* __restrict__ KV,
    const float* __restrict__ ksum, float* __restrict__ attn) {
  __shared__ float sq_s[64][65], sk_s[64][65], v_s[64][65], A_s[64][65],
      Mp_s[64][65];
  __shared__ float zp_s[64];
  int h = blockIdx.x / NC, c = blockIdx.x % NC;
  int tid = threadIdx.x;
  size_t base = (size_t)h * S_LEN * DH + (size_t)c * CHUNK * DH;
  const float* Mp = KV + (size_t)(h * NC + c) * (DH * DH);
#pragma unroll
  for (int i = 0; i < 16; i++) {
    int e = i * 256 + tid;
    int t = e >> 6, d = e & 63;
    sq_s[t][d] = sq_g[base + e];
    sk_s[t][d] = sk_g[base + e];
    v_s[t][d] = v_g[base + e];
    Mp_s[t][d] = Mp[e];
  }
  if (tid < 64) zp_s[tid] = ksum[(h * NC + c) * DH + tid];
  __syncthreads();
  int t = tid >> 2;
  int j0 = (tid & 3) * 16;
  // causal score tile A[t][t'] = sq[t]·sk[t'] for t'<=t
#pragma unroll 4
  for (int j = 0; j < 16; j++) {
    int tp = j0 + j;
    float s = 0.f;
    if (tp <= t) {
      for (int d = 0; d < 64; d++) s += sq_s[t][d] * sk_s[tp][d];
    }
    A_s[t][tp] = s;
  }
  __syncthreads();
  float num[16];
#pragma unroll
  for (int i = 0; i < 16; i++) num[i] = 0.f;
  float den = 0.f;
  for (int d = 0; d < 64; d++) {
    float a = sq_s[t][d];
    den += a * zp_s[d];
#pragma unroll
    for (int i = 0; i < 16; i++) num[i] += a * Mp_s[d][j0 + i];
  }
  for (int tp = 0; tp <= t; tp++) {
    float a = A_s[t][tp];
    den += a;
#pragma unroll
    for (int i = 0; i < 16; i++) num[i] += a * v_s[tp][j0 + i];
  }
  float inv = 1.f / (den + EPS);
  int row = c * CHUNK + t;
#pragma unroll
  for (int i = 0; i < 16; i++)
    attn[(size_t)row * P_DIM + h * DH + j0 + i] = num[i] * inv;
}

// ---------------------------------------------------------------------------
extern "C" void kernel_launch(void* const* d_in, const int* in_sizes, int n_in,
                              void* d_out, int out_size, void* d_ws,
                              size_t ws_size, hipStream_t stream) {
  const float* hs = (const float*)d_in[0];
  const float* Wq = (const float*)d_in[1];
  const float* bq = (const float*)d_in[2];
  const float* Wk = (const float*)d_in[3];
  const float* bk = (const float*)d_in[4];
  const float* Wv = (const float*)d_in[5];
  const float* bv = (const float*)d_in[6];
  const float* Wo = (const float*)d_in[7];
  const float* M_mem = (const float*)d_in[8];
  const float* z_mem = (const float*)d_in[9];
  float* out = (float*)d_out;

  float* ws = (float*)d_ws;
  float* sq = ws;                          // S*P
  float* sk = sq + (size_t)S_LEN * P_DIM;  // S*P
  float* vv = sk + (size_t)S_LEN * P_DIM;  // S*P
  float* KV = vv + (size_t)S_LEN * P_DIM;  // H*NC*64*64
  float* ks = KV + (size_t)H_NUM * NC * DH * DH;  // H*NC*64
  float* attn = ks + (size_t)H_NUM * NC * DH;     // S*P

  dim3 pgrid(S_LEN / 64, P_DIM / 64);
  gemm_kernel<1, 1><<<pgrid, 256, 0, stream>>>(hs, Wq, bq, sq, S_LEN, P_DIM, D_HID);
  gemm_kernel<1, 1><<<pgrid, 256, 0, stream>>>(hs, Wk, bk, sk, S_LEN, P_DIM, D_HID);
  gemm_kernel<0, 1><<<pgrid, 256, 0, stream>>>(hs, Wv, bv, vv, S_LEN, P_DIM, D_HID);

  chunk_sum_kernel<<<H_NUM * NC, 256, 0, stream>>>(sk, vv, KV, ks);
  prefix_kernel<<<H_NUM * 16, 256, 0, stream>>>(KV, ks, M_mem, z_mem);
  attn_chunk_kernel<<<H_NUM * NC, 256, 0, stream>>>(sq, sk, vv, KV, ks, attn);

  dim3 ogrid(S_LEN / 64, D_HID / 64);
  gemm_kernel<0, 0><<<ogrid, 256, 0, stream>>>(attn, Wo, nullptr, out, S_LEN,
                                               D_HID, P_DIM);
}

// Round 2
// 177.932 us; speedup vs baseline: 2.1694x; 2.1694x over previous
//
#include <hip/hip_runtime.h>
#include <hip/hip_bf16.h>
#include <math.h>

// Problem constants (fixed by setup_inputs)
#define S_LEN 4096
#define D_HID 512
#define P_DIM 512
#define H_NUM 8
#define DH 64
#define CHUNK 64
#define NC (S_LEN / CHUNK)   // 64 chunks per head
#define EPS 1e-6f

typedef __attribute__((ext_vector_type(8))) short short8;
typedef __attribute__((ext_vector_type(4))) float f32x4;
typedef __attribute__((ext_vector_type(4))) unsigned short ushort4v;

static __device__ inline float b2f(unsigned short u) {
  return __builtin_bit_cast(float, ((unsigned int)u) << 16);
}
static __device__ inline unsigned short f2b(float f) {
  unsigned int u = __builtin_bit_cast(unsigned int, f);
  u = (u + 0x7fff + ((u >> 16) & 1)) >> 16;  // round-nearest-even
  return (unsigned short)u;
}

#define GLOAD_LDS16(g, l)                                              \
  __builtin_amdgcn_global_load_lds(                                    \
      (const __attribute__((address_space(1))) unsigned int*)(g),      \
      (__attribute__((address_space(3))) unsigned int*)(l), 16, 0, 0)

// ---------------------------------------------------------------------------
// hs fp32 -> bf16
// ---------------------------------------------------------------------------
__global__ __launch_bounds__(256) void convert_hs(
    const float4* __restrict__ in, unsigned short* __restrict__ out, int n4) {
  int idx = blockIdx.x * 256 + threadIdx.x;
  if (idx < n4) {
    float4 v = in[idx];
    ushort4v o = {f2b(v.x), f2b(v.y), f2b(v.z), f2b(v.w)};
    *(ushort4v*)(out + (size_t)idx * 4) = o;
  }
}

// ---------------------------------------------------------------------------
// Transpose+convert 512x512 fp32 weights -> WT[z][n][k] bf16 (z: q,k,v,o)
// ---------------------------------------------------------------------------
__global__ __launch_bounds__(256) void transpose_w(
    const float* __restrict__ Wq, const float* __restrict__ Wk,
    const float* __restrict__ Wv, const float* __restrict__ Wo,
    unsigned short* __restrict__ WT) {
  __shared__ float t[32][33];
  int z = blockIdx.z;
  const float* src = (z == 0) ? Wq : (z == 1) ? Wk : (z == 2) ? Wv : Wo;
  int bx = blockIdx.x * 32;  // src col block (n)
  int by = blockIdx.y * 32;  // src row block (k)
  int lx = threadIdx.x & 31, ly = threadIdx.x >> 5;
#pragma unroll
  for (int i = 0; i < 4; i++)
    t[ly + i * 8][lx] = src[(size_t)(by + ly + i * 8) * 512 + bx + lx];
  __syncthreads();
#pragma unroll
  for (int i = 0; i < 4; i++) {
    int n = bx + ly + i * 8;
    WT[((size_t)z * 512 + n) * 512 + by + lx] = f2b(t[lx][ly + i * 8]);
  }
}

// ---------------------------------------------------------------------------
// MFMA bf16 GEMM, 128x128 tile, BK=32, 4 waves (2x2), 16x16x32 MFMA.
// MODE 0: A=hs_bf [4096,512], BT=WTcat [1536,512]; bias+elu+1 for n<1024;
//         writes head-split bf16 sq/sk/vv [8][4096][64].
// MODE 1: A=attn_bf [4096,512], BT=WoT [512,512]; writes fp32 out [4096,512].
// ---------------------------------------------------------------------------
template <int MODE>
__global__ __launch_bounds__(256) void mfma_gemm(
    const unsigned short* __restrict__ A, const unsigned short* __restrict__ BT,
    const float* __restrict__ bq, const float* __restrict__ bk,
    const float* __restrict__ bv, unsigned short* __restrict__ o0,
    unsigned short* __restrict__ o1, unsigned short* __restrict__ o2,
    float* __restrict__ outf) {
  __shared__ unsigned short As[128 * 32];
  __shared__ unsigned short Bs[128 * 32];
  int tid = threadIdx.x;
  int w = tid >> 6, lane = tid & 63;
  int bm = blockIdx.x * 128, bn = blockIdx.y * 128;
  f32x4 acc[4][4] = {};

  int ldrow = lane >> 2;          // 0..15
  int ldk = (lane & 3) * 8;       // 0,8,16,24

  for (int k0 = 0; k0 < 512; k0 += 32) {
#pragma unroll
    for (int i = 0; i < 2; i++) {
      int seg = i * 4 + w;  // 0..7, wave-uniform
      int row = seg * 16 + ldrow;
      GLOAD_LDS16(A + (size_t)(bm + row) * 512 + k0 + ldk, As + seg * 512);
      GLOAD_LDS16(BT + (size_t)(bn + row) * 512 + k0 + ldk, Bs + seg * 512);
    }
    __syncthreads();  // compiler emits vmcnt(0) drain before barrier

    int wr = w >> 1, wc = w & 1;
    short8 a[4], b[4];
#pragma unroll
    for (int m = 0; m < 4; m++) {
      int arow = wr * 64 + m * 16 + (lane & 15);
      a[m] = *(const short8*)(As + arow * 32 + (lane >> 4) * 8);
    }
#pragma unroll
    for (int n = 0; n < 4; n++) {
      int brow = wc * 64 + n * 16 + (lane & 15);
      b[n] = *(const short8*)(Bs + brow * 32 + (lane >> 4) * 8);
    }
#pragma unroll
    for (int m = 0; m < 4; m++)
#pragma unroll
      for (int n = 0; n < 4; n++)
        acc[m][n] =
            __builtin_amdgcn_mfma_f32_16x16x32_bf16(a[m], b[n], acc[m][n], 0, 0, 0);
    __syncthreads();
  }

  int wr = w >> 1, wc = w & 1;
#pragma unroll
  for (int m = 0; m < 4; m++) {
    int r0 = bm + wr * 64 + m * 16 + ((lane >> 4) << 2);
#pragma unroll
    for (int n = 0; n < 4; n++) {
      int col = bn + wc * 64 + n * 16 + (lane & 15);
      if (MODE == 0) {
        int m512 = col & 511;
        int h = m512 >> 6, d = m512 & 63;
        float bias = (col < 512) ? bq[m512] : (col < 1024 ? bk[m512] : bv[m512]);
        unsigned short* dst = (col < 512) ? o0 : (col < 1024 ? o1 : o2);
#pragma unroll
        for (int j = 0; j < 4; j++) {
          float val = acc[m][n][j] + bias;
          if (col < 1024) val = (val > 0.f) ? (val + 1.f) : __expf(val);
          dst[((size_t)h * S_LEN + (r0 + j)) * 64 + d] = f2b(val);
        }
      } else {
#pragma unroll
        for (int j = 0; j < 4; j++)
          outf[(size_t)(r0 + j) * 512 + col] = acc[m][n][j];
      }
    }
  }
}

// ---------------------------------------------------------------------------
// Per-(head,chunk) KV outer-product sum and k sum (bf16 inputs, fp32 accum).
// ---------------------------------------------------------------------------
__global__ __launch_bounds__(256) void chunk_sum_kernel(
    const unsigned short* __restrict__ sk_g, const unsigned short* __restrict__ v_g,
    float* __restrict__ KV, float* __restrict__ ksum) {
  __shared__ float sk_s[64][65], v_s[64][65];
  int h = blockIdx.x / NC, c = blockIdx.x % NC;
  int tid = threadIdx.x;
  size_t base = (size_t)h * S_LEN * DH + (size_t)c * CHUNK * DH;
  {
    int t0 = tid >> 2, d0 = (tid & 3) * 16;
    const short8* ps = (const short8*)(sk_g + base + (size_t)t0 * 64 + d0);
    const short8* pv = (const short8*)(v_g + base + (size_t)t0 * 64 + d0);
    short8 s0 = ps[0], s1 = ps[1], w0 = pv[0], w1 = pv[1];
#pragma unroll
    for (int j = 0; j < 8; j++) {
      sk_s[t0][d0 + j] = b2f((unsigned short)s0[j]);
      sk_s[t0][d0 + 8 + j] = b2f((unsigned short)s1[j]);
      v_s[t0][d0 + j] = b2f((unsigned short)w0[j]);
      v_s[t0][d0 + 8 + j] = b2f((unsigned short)w1[j]);
    }
  }
  __syncthreads();
  int e = tid & 63, db = (tid >> 6) * 16;
  float acc[16] = {};
  for (int t = 0; t < 64; t++) {
    float ve = v_s[t][e];
#pragma unroll
    for (int i = 0; i < 16; i++) acc[i] += sk_s[t][db + i] * ve;
  }
  float* outp = KV + (size_t)(h * NC + c) * (DH * DH);
#pragma unroll
  for (int i = 0; i < 16; i++) outp[(db + i) * 64 + e] = acc[i];
  if (tid < 64) {
    float s = 0.f;
    for (int t = 0; t < 64; t++) s += sk_s[t][tid];
    ksum[(h * NC + c) * DH + tid] = s;
  }
}

// ---------------------------------------------------------------------------
// In-place exclusive prefix over chunks, seeded by persistent memory.
// ---------------------------------------------------------------------------
__global__ __launch_bounds__(256) void prefix_kernel(
    float* __restrict__ KV, float* __restrict__ ksum,
    const float* __restrict__ M_mem, const float* __restrict__ z_mem) {
  int h = blockIdx.x >> 4, g = blockIdx.x & 15;
  int tid = threadIdx.x;
  int entry = g * 256 + tid;  // 0..4095
  float pref = M_mem[h * (DH * DH) + entry];
  for (int c = 0; c < NC; c++) {
    float* p = KV + (size_t)(h * NC + c) * (DH * DH) + entry;
    float val = *p;
    *p = pref;
    pref += val;
  }
  if (g == 0 && tid < 64) {
    float zp = z_mem[h * DH + tid];
    for (int c = 0; c < NC; c++) {
      float* p = ksum + (h * NC + c) * DH + tid;
      float val = *p;
      *p = zp;
      zp += val;
    }
  }
}

// ---------------------------------------------------------------------------
// Per-(head,chunk) output: inter part via M_prefix, intra causal part.
// Writes attn as bf16 head-merged [S][512] for the output GEMM.
// ---------------------------------------------------------------------------
__global__ __launch_bounds__(256) void attn_chunk_kernel(
    const unsigned short* __restrict__ sq_g, const unsigned short* __restrict__ sk_g,
    const unsigned short* __restrict__ v_g, const float* __restrict__ KV,
    const float* __restrict__ ksum, unsigned short* __restrict__ attn) {
  __shared__ float sq_s[64][65], sk_s[64][65], v_s[64][65], A_s[64][65],
      Mp_s[64][65];
  __shared__ float zp_s[64];
  int h = blockIdx.x / NC, c = blockIdx.x % NC;
  int tid = threadIdx.x;
  size_t base = (size_t)h * S_LEN * DH + (size_t)c * CHUNK * DH;
  const float* Mp = KV + (size_t)(h * NC + c) * (DH * DH);
  {
    int t0 = tid >> 2, d0 = (tid & 3) * 16;
    const short8* pq = (const short8*)(sq_g + base + (size_t)t0 * 64 + d0);
    const short8* ps = (const short8*)(sk_g + base + (size_t)t0 * 64 + d0);
    const short8* pv = (const short8*)(v_g + base + (size_t)t0 * 64 + d0);
    short8 q0 = pq[0], q1 = pq[1], s0 = ps[0], s1 = ps[1], w0 = pv[0], w1 = pv[1];
#pragma unroll
    for (int j = 0; j < 8; j++) {
      sq_s[t0][d0 + j] = b2f((unsigned short)q0[j]);
      sq_s[t0][d0 + 8 + j] = b2f((unsigned short)q1[j]);
      sk_s[t0][d0 + j] = b2f((unsigned short)s0[j]);
      sk_s[t0][d0 + 8 + j] = b2f((unsigned short)s1[j]);
      v_s[t0][d0 + j] = b2f((unsigned short)w0[j]);
      v_s[t0][d0 + 8 + j] = b2f((unsigned short)w1[j]);
    }
  }
#pragma unroll
  for (int i = 0; i < 16; i++) {
    int e = i * 256 + tid;
    Mp_s[e >> 6][e & 63] = Mp[e];
  }
  if (tid < 64) zp_s[tid] = ksum[(h * NC + c) * DH + tid];
  __syncthreads();
  int t = tid >> 2;
  int j0 = (tid & 3) * 16;
  // causal score tile A[t][t'] = sq[t]·sk[t'] for t'<=t
#pragma unroll 4
  for (int j = 0; j < 16; j++) {
    int tp = j0 + j;
    float s = 0.f;
    if (tp <= t) {
      for (int d = 0; d < 64; d++) s += sq_s[t][d] * sk_s[tp][d];
    }
    A_s[t][tp] = s;
  }
  __syncthreads();
  float num[16];
#pragma unroll
  for (int i = 0; i < 16; i++) num[i] = 0.f;
  float den = 0.f;
  for (int d = 0; d < 64; d++) {
    float a = sq_s[t][d];
    den += a * zp_s[d];
#pragma unroll
    for (int i = 0; i < 16; i++) num[i] += a * Mp_s[d][j0 + i];
  }
  for (int tp = 0; tp <= t; tp++) {
    float a = A_s[t][tp];
    den += a;
#pragma unroll
    for (int i = 0; i < 16; i++) num[i] += a * v_s[tp][j0 + i];
  }
  float inv = 1.f / (den + EPS);
  int row = c * CHUNK + t;
  short8 oa, ob;
#pragma unroll
  for (int i = 0; i < 8; i++) {
    oa[i] = (short)f2b(num[i] * inv);
    ob[i] = (short)f2b(num[8 + i] * inv);
  }
  short8* dst = (short8*)(attn + (size_t)row * P_DIM + h * DH + j0);
  dst[0] = oa;
  dst[1] = ob;
}

// ---------------------------------------------------------------------------
extern "C" void kernel_launch(void* const* d_in, const int* in_sizes, int n_in,
                              void* d_out, int out_size, void* d_ws,
                              size_t ws_size, hipStream_t stream) {
  const float* hs = (const float*)d_in[0];
  const float* Wq = (const float*)d_in[1];
  const float* bq = (const float*)d_in[2];
  const float* Wk = (const float*)d_in[3];
  const float* bk = (const float*)d_in[4];
  const float* Wv = (const float*)d_in[5];
  const float* bv = (const float*)d_in[6];
  const float* Wo = (const float*)d_in[7];
  const float* M_mem = (const float*)d_in[8];
  const float* z_mem = (const float*)d_in[9];
  float* out = (float*)d_out;

  // workspace layout (bf16 region first, then fp32 region) ~30 MB
  unsigned short* hs_bf = (unsigned short*)d_ws;        // 4096*512
  unsigned short* WT = hs_bf + (size_t)S_LEN * D_HID;   // 4*512*512 (q,k,v,o^T)
  unsigned short* sq = WT + (size_t)4 * 512 * 512;      // [8][4096][64]
  unsigned short* sk = sq + (size_t)H_NUM * S_LEN * DH;
  unsigned short* vv = sk + (size_t)H_NUM * S_LEN * DH;
  unsigned short* attnb = vv + (size_t)H_NUM * S_LEN * DH;  // [4096][512]
  float* KV = (float*)(attnb + (size_t)S_LEN * P_DIM);      // 8*64*64*64
  float* ks = KV + (size_t)H_NUM * NC * DH * DH;            // 8*64*64

  convert_hs<<<2048, 256, 0, stream>>>((const float4*)hs, hs_bf,
                                       S_LEN * D_HID / 4);
  dim3 tg(16, 16, 4);
  transpose_w<<<tg, 256, 0, stream>>>(Wq, Wk, Wv, Wo, WT);

  dim3 pg(S_LEN / 128, 1536 / 128);
  mfma_gemm<0><<<pg, 256, 0, stream>>>(hs_bf, WT, bq, bk, bv, sq, sk, vv,
                                       nullptr);

  chunk_sum_kernel<<<H_NUM * NC, 256, 0, stream>>>(sk, vv, KV, ks);
  prefix_kernel<<<H_NUM * 16, 256, 0, stream>>>(KV, ks, M_mem, z_mem);
  attn_chunk_kernel<<<H_NUM * NC, 256, 0, stream>>>(sq, sk, vv, KV, ks, attnb);

  dim3 og(S_LEN / 128, 512 / 128);
  mfma_gemm<1><<<og, 256, 0, stream>>>(attnb, WT + (size_t)3 * 512 * 512,
                                       nullptr, nullptr, nullptr, nullptr,
                                       nullptr, nullptr, out);
}

// Round 3
// 136.037 us; speedup vs baseline: 2.8375x; 1.3080x over previous
//
#include <hip/hip_runtime.h>
#include <hip/hip_bf16.h>
#include <math.h>

// Problem constants (fixed by setup_inputs)
#define S_LEN 4096
#define D_HID 512
#define P_DIM 512
#define H_NUM 8
#define DH 64
#define NC 64          // chunks per head (chunk = 64 rows)
#define EPS 1e-6f

typedef __attribute__((ext_vector_type(8))) short short8;
typedef __attribute__((ext_vector_type(4))) float f32x4;
typedef __attribute__((ext_vector_type(4))) unsigned short ushort4v;

static __device__ __forceinline__ float b2f(unsigned short u) {
  return __builtin_bit_cast(float, ((unsigned int)u) << 16);
}
static __device__ __forceinline__ unsigned short f2b(float f) {
  unsigned int u = __builtin_bit_cast(unsigned int, f);
  u = (u + 0x7fff + ((u >> 16) & 1)) >> 16;  // round-nearest-even
  return (unsigned short)u;
}
// XOR swizzle: element index within a 64-elem (128B) bf16 row
static __device__ __forceinline__ int swz(int row, int d) {
  return d ^ ((row & 7) << 3);
}

#define GLOAD_LDS16(g, l)                                              \
  __builtin_amdgcn_global_load_lds(                                    \
      (const __attribute__((address_space(1))) unsigned int*)(g),      \
      (__attribute__((address_space(3))) unsigned int*)(l), 16, 0, 0)

// ---------------------------------------------------------------------------
// hs fp32 -> bf16
// ---------------------------------------------------------------------------
__global__ __launch_bounds__(256) void convert_hs(
    const float4* __restrict__ in, unsigned short* __restrict__ out, int n4) {
  int idx = blockIdx.x * 256 + threadIdx.x;
  if (idx < n4) {
    float4 v = in[idx];
    ushort4v o = {f2b(v.x), f2b(v.y), f2b(v.z), f2b(v.w)};
    *(ushort4v*)(out + (size_t)idx * 4) = o;
  }
}

// ---------------------------------------------------------------------------
// Transpose+convert 512x512 fp32 weights -> WT[z][n][k] bf16 (z: q,k,v,o)
// ---------------------------------------------------------------------------
__global__ __launch_bounds__(256) void transpose_w(
    const float* __restrict__ Wq, const float* __restrict__ Wk,
    const float* __restrict__ Wv, const float* __restrict__ Wo,
    unsigned short* __restrict__ WT) {
  __shared__ float t[32][33];
  int z = blockIdx.z;
  const float* src = (z == 0) ? Wq : (z == 1) ? Wk : (z == 2) ? Wv : Wo;
  int bx = blockIdx.x * 32;  // src col block (n)
  int by = blockIdx.y * 32;  // src row block (k)
  int lx = threadIdx.x & 31, ly = threadIdx.x >> 5;
#pragma unroll
  for (int i = 0; i < 4; i++)
    t[ly + i * 8][lx] = src[(size_t)(by + ly + i * 8) * 512 + bx + lx];
  __syncthreads();
#pragma unroll
  for (int i = 0; i < 4; i++) {
    int n = bx + ly + i * 8;
    WT[((size_t)z * 512 + n) * 512 + by + lx] = f2b(t[lx][ly + i * 8]);
  }
}

// ---------------------------------------------------------------------------
// MFMA bf16 GEMM, 128x128 tile, BK=32, 4 waves (2x2), 16x16x32 MFMA.
// MODE 0: A=hs_bf[4096,512], BT=WTcat[1536,512]; bias; elu+1 for q,k.
//   writes: sqz  [8][4096][64] bf16, row-swizzled
//           skz  [8][4096][64] bf16, row-swizzled
//           skTz [8][64][4096] bf16, transposed, row-swizzled per 64-chunk
//           vTz  [8][64][4096] bf16, transposed, row-swizzled per 64-chunk
// MODE 1: A=attnb[4096,512], BT=WoT[512,512]; writes fp32 out.
// ---------------------------------------------------------------------------
template <int MODE>
__global__ __launch_bounds__(256) void mfma_gemm(
    const unsigned short* __restrict__ A, const unsigned short* __restrict__ BT,
    const float* __restrict__ bq, const float* __restrict__ bk,
    const float* __restrict__ bv, unsigned short* __restrict__ sqz,
    unsigned short* __restrict__ skz, unsigned short* __restrict__ skTz,
    unsigned short* __restrict__ vTz, float* __restrict__ outf) {
  __shared__ unsigned short As[128 * 32];
  __shared__ unsigned short Bs[128 * 32];
  int tid = threadIdx.x;
  int w = tid >> 6, lane = tid & 63;
  int bm = blockIdx.x * 128, bn = blockIdx.y * 128;
  f32x4 acc[4][4] = {};

  int ldrow = lane >> 2;     // 0..15
  int ldk = (lane & 3) * 8;  // 0,8,16,24

  for (int k0 = 0; k0 < 512; k0 += 32) {
#pragma unroll
    for (int i = 0; i < 2; i++) {
      int seg = i * 4 + w;  // 0..7, wave-uniform
      int row = seg * 16 + ldrow;
      GLOAD_LDS16(A + (size_t)(bm + row) * 512 + k0 + ldk, As + seg * 512);
      GLOAD_LDS16(BT + (size_t)(bn + row) * 512 + k0 + ldk, Bs + seg * 512);
    }
    __syncthreads();

    int wr = w >> 1, wc = w & 1;
    short8 a[4], b[4];
#pragma unroll
    for (int m = 0; m < 4; m++) {
      int arow = wr * 64 + m * 16 + (lane & 15);
      a[m] = *(const short8*)(As + arow * 32 + (lane >> 4) * 8);
    }
#pragma unroll
    for (int n = 0; n < 4; n++) {
      int brow = wc * 64 + n * 16 + (lane & 15);
      b[n] = *(const short8*)(Bs + brow * 32 + (lane >> 4) * 8);
    }
#pragma unroll
    for (int m = 0; m < 4; m++)
#pragma unroll
      for (int n = 0; n < 4; n++)
        acc[m][n] = __builtin_amdgcn_mfma_f32_16x16x32_bf16(a[m], b[n],
                                                            acc[m][n], 0, 0, 0);
    __syncthreads();
  }

  int wr = w >> 1, wc = w & 1;
#pragma unroll
  for (int m = 0; m < 4; m++) {
    int r0 = bm + wr * 64 + m * 16 + ((lane >> 4) << 2);
#pragma unroll
    for (int n = 0; n < 4; n++) {
      int col = bn + wc * 64 + n * 16 + (lane & 15);
      if (MODE == 0) {
        int m512 = col & 511, hh = m512 >> 6, dd = m512 & 63;
        float bias = (col < 512) ? bq[m512] : (col < 1024 ? bk[m512] : bv[m512]);
#pragma unroll
        for (int j = 0; j < 4; j++) {
          int s = r0 + j;
          float val = acc[m][n][j] + bias;
          if (col < 1024) val = (val > 0.f) ? (val + 1.f) : __expf(val);
          unsigned short bb = f2b(val);
          size_t tpos = ((size_t)hh * 64 + dd) * S_LEN + (s & ~63) +
                        ((s & 63) ^ ((dd & 7) << 3));
          if (col < 512) {
            sqz[((size_t)hh * S_LEN + s) * 64 + swz(s, dd)] = bb;
          } else if (col < 1024) {
            skz[((size_t)hh * S_LEN + s) * 64 + swz(s, dd)] = bb;
            skTz[tpos] = bb;
          } else {
            vTz[tpos] = bb;
          }
        }
      } else {
#pragma unroll
        for (int j = 0; j < 4; j++)
          outf[(size_t)(r0 + j) * 512 + col] = acc[m][n][j];
      }
    }
  }
}

// ---------------------------------------------------------------------------
// Per-(head,chunk) MFMA: KVt[e][d] = sum_t v[t][e]*sk[t][d]  (A=vT, BT=skT)
// ones-row trick (A row 64 = 1) gives ksum[d] = sum_t sk[t][d] in C row 64.
// ---------------------------------------------------------------------------
__global__ __launch_bounds__(256) void chunk_sum_mfma(
    const unsigned short* __restrict__ vTz, const unsigned short* __restrict__ skTz,
    float* __restrict__ KVt, float* __restrict__ ksum) {
  __shared__ unsigned short vt_lds[64 * 64];
  __shared__ unsigned short skt_lds[64 * 64];
  int h = blockIdx.x / NC, c = blockIdx.x % NC;
  int tid = threadIdx.x, w = tid >> 6, lane = tid & 63;
  int lr = lane >> 3, lc = (lane & 7) * 8;
#pragma unroll
  for (int i = 0; i < 2; i++) {
    int seg = w * 2 + i;
    GLOAD_LDS16(vTz + ((size_t)h * 64 + seg * 8 + lr) * S_LEN + c * 64 + lc,
                vt_lds + seg * 512);
    GLOAD_LDS16(skTz + ((size_t)h * 64 + seg * 8 + lr) * S_LEN + c * 64 + lc,
                skt_lds + seg * 512);
  }
  __syncthreads();

  int fr = lane & 15, kg = (lane >> 4) * 8;
  short8 onesA = {};
  if (fr == 0) {
#pragma unroll
    for (int j = 0; j < 8; j++) onesA[j] = (short)0x3F80;
  }
  f32x4 acc[4] = {};
  f32x4 accK[4] = {};
#pragma unroll
  for (int k0 = 0; k0 < 64; k0 += 32) {
    int e = w * 16 + fr;
    short8 a = *(const short8*)(vt_lds + e * 64 + ((k0 + kg) ^ ((e & 7) << 3)));
    short8 b[4];
#pragma unroll
    for (int nt = 0; nt < 4; nt++) {
      int d = nt * 16 + fr;
      b[nt] = *(const short8*)(skt_lds + d * 64 + ((k0 + kg) ^ ((d & 7) << 3)));
    }
#pragma unroll
    for (int nt = 0; nt < 4; nt++)
      acc[nt] = __builtin_amdgcn_mfma_f32_16x16x32_bf16(a, b[nt], acc[nt], 0, 0, 0);
    if (w == 0) {
#pragma unroll
      for (int nt = 0; nt < 4; nt++)
        accK[nt] =
            __builtin_amdgcn_mfma_f32_16x16x32_bf16(onesA, b[nt], accK[nt], 0, 0, 0);
    }
  }
  int e0 = w * 16 + (lane >> 4) * 4;
  size_t base = (size_t)(h * NC + c) * 4096;
#pragma unroll
  for (int nt = 0; nt < 4; nt++)
#pragma unroll
    for (int j = 0; j < 4; j++)
      KVt[base + (size_t)(e0 + j) * 64 + nt * 16 + fr] = acc[nt][j];
  if (w == 0 && lane < 16) {
#pragma unroll
    for (int nt = 0; nt < 4; nt++)
      ksum[(size_t)(h * NC + c) * 64 + nt * 16 + lane] = accK[nt][0];
  }
}

// ---------------------------------------------------------------------------
// Exclusive prefix over chunks (seeded by M_mem/z_mem), emitted as swizzled
// bf16 KVpz[h][c][e][swz(e,d)] and zp_bf[h][c][d].
// ---------------------------------------------------------------------------
__global__ __launch_bounds__(256) void prefix_kernel(
    const float* __restrict__ KVt, const float* __restrict__ ksum,
    const float* __restrict__ M_mem, const float* __restrict__ z_mem,
    unsigned short* __restrict__ KVpz, unsigned short* __restrict__ zp_bf) {
  int h = blockIdx.x >> 4, g = blockIdx.x & 15;
  int tid = threadIdx.x;
  int entry = g * 256 + tid, e = entry >> 6, d = entry & 63;
  float pref = M_mem[h * 4096 + d * 64 + e];  // M_mem[h][d][e] seeds KVt[e][d]
  size_t i0 = (size_t)(h * NC) * 4096 + (size_t)e * 64 + d;
  size_t o0 = (size_t)(h * NC) * 4096 + (size_t)e * 64 + swz(e, d);
  for (int c = 0; c < NC; c += 4) {
    float v0 = KVt[i0 + (size_t)c * 4096];
    float v1 = KVt[i0 + (size_t)(c + 1) * 4096];
    float v2 = KVt[i0 + (size_t)(c + 2) * 4096];
    float v3 = KVt[i0 + (size_t)(c + 3) * 4096];
    KVpz[o0 + (size_t)c * 4096] = f2b(pref);
    pref += v0;
    KVpz[o0 + (size_t)(c + 1) * 4096] = f2b(pref);
    pref += v1;
    KVpz[o0 + (size_t)(c + 2) * 4096] = f2b(pref);
    pref += v2;
    KVpz[o0 + (size_t)(c + 3) * 4096] = f2b(pref);
    pref += v3;
  }
  if (g == 0 && tid < 64) {
    float zp = z_mem[h * 64 + tid];
    for (int c = 0; c < NC; c += 4) {
      float u0 = ksum[(size_t)(h * NC + c) * 64 + tid];
      float u1 = ksum[(size_t)(h * NC + c + 1) * 64 + tid];
      float u2 = ksum[(size_t)(h * NC + c + 2) * 64 + tid];
      float u3 = ksum[(size_t)(h * NC + c + 3) * 64 + tid];
      zp_bf[(size_t)(h * NC + c) * 64 + tid] = f2b(zp);
      zp += u0;
      zp_bf[(size_t)(h * NC + c + 1) * 64 + tid] = f2b(zp);
      zp += u1;
      zp_bf[(size_t)(h * NC + c + 2) * 64 + tid] = f2b(zp);
      zp += u2;
      zp_bf[(size_t)(h * NC + c + 3) * 64 + tid] = f2b(zp);
      zp += u3;
    }
  }
}

// ---------------------------------------------------------------------------
// Per-(head,chunk) attention, all-MFMA.
// Stage 1: S = sq @ sk^T (64x64x64), causal-masked, split hi/lo bf16.
// Stage 2: [Shi|Slo|sq](64x192) @ [v|v|Mp](192x80) -> num (cols 0..63),
//          den (col 64 via ones/zp column). out = num/(den+eps) -> attnb bf16.
// ---------------------------------------------------------------------------
__global__ __launch_bounds__(256) void attn_mfma(
    const unsigned short* __restrict__ sqz, const unsigned short* __restrict__ skz,
    const unsigned short* __restrict__ vTz, const unsigned short* __restrict__ KVpz,
    const unsigned short* __restrict__ zp_bf, unsigned short* __restrict__ attnb) {
  __shared__ unsigned short sq_lds[4096], sk_lds[4096];
  __shared__ unsigned short btv_lds[80 * 64], btm_lds[80 * 64];
  __shared__ unsigned short shi_lds[4096], slo_lds[4096];
  int h = blockIdx.x / NC, c = blockIdx.x % NC;
  int tid = threadIdx.x, w = tid >> 6, lane = tid & 63;

  {
    const unsigned short* sq_g = sqz + ((size_t)h * S_LEN + c * 64) * 64;
    const unsigned short* sk_g = skz + ((size_t)h * S_LEN + c * 64) * 64;
    const unsigned short* km_g = KVpz + (size_t)(h * NC + c) * 4096;
    int lr = lane >> 3, lc = (lane & 7) * 8;
#pragma unroll
    for (int i = 0; i < 2; i++) {
      int seg = w * 2 + i;
      GLOAD_LDS16(sq_g + seg * 512 + lane * 8, sq_lds + seg * 512);
      GLOAD_LDS16(sk_g + seg * 512 + lane * 8, sk_lds + seg * 512);
      GLOAD_LDS16(km_g + seg * 512 + lane * 8, btm_lds + seg * 512);
      GLOAD_LDS16(vTz + ((size_t)h * 64 + seg * 8 + lr) * S_LEN + c * 64 + lc,
                  btv_lds + seg * 512);
    }
  }
  if (tid < 8) {  // row 64: ones column (den intra) and zp column (den inter)
    short8 one;
#pragma unroll
    for (int j = 0; j < 8; j++) one[j] = (short)0x3F80;
    *(short8*)(btv_lds + 64 * 64 + tid * 8) = one;
    *(short8*)(btm_lds + 64 * 64 + tid * 8) =
        *(const short8*)(zp_bf + (size_t)(h * NC + c) * 64 + tid * 8);
  }
  __syncthreads();

  int fr = lane & 15, kg8 = (lane >> 4) * 8;
  int ta = w * 16 + fr;              // a-frag row
  int sw_a = (ta & 7) << 3;

  // ---- stage 1: S = sq @ sk^T ----
  f32x4 accS[4] = {};
#pragma unroll
  for (int k0 = 0; k0 < 64; k0 += 32) {
    short8 a = *(const short8*)(sq_lds + ta * 64 + ((k0 + kg8) ^ sw_a));
#pragma unroll
    for (int nt = 0; nt < 4; nt++) {
      int tp = nt * 16 + fr;
      short8 b = *(const short8*)(sk_lds + tp * 64 + ((k0 + kg8) ^ ((tp & 7) << 3)));
      accS[nt] = __builtin_amdgcn_mfma_f32_16x16x32_bf16(a, b, accS[nt], 0, 0, 0);
    }
  }
  // ---- mask + hi/lo split, write to LDS (own rows only -> no barrier) ----
  int r0 = (lane >> 4) * 4;
#pragma unroll
  for (int nt = 0; nt < 4; nt++) {
    int tp = nt * 16 + fr;
#pragma unroll
    for (int j = 0; j < 4; j++) {
      int t = w * 16 + r0 + j;
      float s = (tp <= t) ? accS[nt][j] : 0.f;
      unsigned short hi = f2b(s);
      unsigned short lo = f2b(s - b2f(hi));
      shi_lds[t * 64 + swz(t, tp)] = hi;
      slo_lds[t * 64 + swz(t, tp)] = lo;
    }
  }
  // ---- stage 2: [Shi|Slo|sq] @ [v|v|Mp] ----
  f32x4 acc2[5] = {};
#pragma unroll
  for (int ks = 0; ks < 6; ks++) {
    const unsigned short* asrc = (ks < 2) ? shi_lds : (ks < 4) ? slo_lds : sq_lds;
    const unsigned short* bsrc = (ks < 4) ? btv_lds : btm_lds;
    int ak = (ks & 1) * 32 + kg8;
    short8 a = *(const short8*)(asrc + ta * 64 + (ak ^ sw_a));
#pragma unroll
    for (int nt = 0; nt < 5; nt++) {
      int n = nt * 16 + fr;
      short8 b = *(const short8*)(bsrc + n * 64 + (ak ^ ((n & 7) << 3)));
      acc2[nt] = __builtin_amdgcn_mfma_f32_16x16x32_bf16(a, b, acc2[nt], 0, 0, 0);
    }
  }
  // ---- den broadcast + write ----
  float inv[4];
#pragma unroll
  for (int j = 0; j < 4; j++) {
    float dj = __shfl(acc2[4][j], (lane & 48), 64);
    inv[j] = 1.f / (dj + EPS);
  }
  int srow = c * 64 + w * 16 + r0;
#pragma unroll
  for (int nt = 0; nt < 4; nt++) {
    int col = h * 64 + nt * 16 + fr;
#pragma unroll
    for (int j = 0; j < 4; j++)
      attnb[(size_t)(srow + j) * 512 + col] = f2b(acc2[nt][j] * inv[j]);
  }
}

// ---------------------------------------------------------------------------
extern "C" void kernel_launch(void* const* d_in, const int* in_sizes, int n_in,
                              void* d_out, int out_size, void* d_ws,
                              size_t ws_size, hipStream_t stream) {
  const float* hs = (const float*)d_in[0];
  const float* Wq = (const float*)d_in[1];
  const float* bq = (const float*)d_in[2];
  const float* Wk = (const float*)d_in[3];
  const float* bk = (const float*)d_in[4];
  const float* Wv = (const float*)d_in[5];
  const float* bv = (const float*)d_in[6];
  const float* Wo = (const float*)d_in[7];
  const float* M_mem = (const float*)d_in[8];
  const float* z_mem = (const float*)d_in[9];
  float* out = (float*)d_out;

  // workspace layout (~38 MB; ws proved >= 72 MB by round-1 fp32 version)
  unsigned short* hs_bf = (unsigned short*)d_ws;           // 2M sh
  unsigned short* WT = hs_bf + (size_t)S_LEN * D_HID;      // 1M sh
  unsigned short* sqz = WT + (size_t)4 * 512 * 512;        // 2M sh
  unsigned short* skz = sqz + (size_t)H_NUM * S_LEN * DH;  // 2M sh
  unsigned short* skTz = skz + (size_t)H_NUM * S_LEN * DH; // 2M sh
  unsigned short* vTz = skTz + (size_t)H_NUM * S_LEN * DH; // 2M sh
  unsigned short* attnb = vTz + (size_t)H_NUM * S_LEN * DH;       // 2M sh
  unsigned short* KVpz = attnb + (size_t)S_LEN * P_DIM;           // 2M sh
  unsigned short* zp_bf = KVpz + (size_t)H_NUM * NC * DH * DH;    // 32K sh
  float* KVt = (float*)(zp_bf + (size_t)H_NUM * NC * DH);         // 2M f
  float* ksum = KVt + (size_t)H_NUM * NC * DH * DH;               // 32K f

  convert_hs<<<2048, 256, 0, stream>>>((const float4*)hs, hs_bf,
                                       S_LEN * D_HID / 4);
  dim3 tg(16, 16, 4);
  transpose_w<<<tg, 256, 0, stream>>>(Wq, Wk, Wv, Wo, WT);

  dim3 pg(S_LEN / 128, 1536 / 128);
  mfma_gemm<0><<<pg, 256, 0, stream>>>(hs_bf, WT, bq, bk, bv, sqz, skz, skTz,
                                       vTz, nullptr);

  chunk_sum_mfma<<<H_NUM * NC, 256, 0, stream>>>(vTz, skTz, KVt, ksum);
  prefix_kernel<<<H_NUM * 16, 256, 0, stream>>>(KVt, ksum, M_mem, z_mem, KVpz,
                                                zp_bf);
  attn_mfma<<<H_NUM * NC, 256, 0, stream>>>(sqz, skz, vTz, KVpz, zp_bf, attnb);

  dim3 og(S_LEN / 128, 512 / 128);
  mfma_gemm<1><<<og, 256, 0, stream>>>(attnb, WT + (size_t)3 * 512 * 512,
                                       nullptr, nullptr, nullptr, nullptr,
                                       nullptr, nullptr, nullptr, out);
}

// Round 5
// 126.067 us; speedup vs baseline: 3.0619x; 1.0791x over previous
//
#include <hip/hip_runtime.h>
#include <hip/hip_bf16.h>
#include <math.h>

// Problem constants (fixed by setup_inputs)
#define S_LEN 4096
#define D_HID 512
#define P_DIM 512
#define H_NUM 8
#define DH 64
#define NC 64          // chunks per head (chunk = 64 rows)
#define EPS 1e-6f

typedef __attribute__((ext_vector_type(8))) short short8;
typedef __attribute__((ext_vector_type(4))) float f32x4;
typedef __attribute__((ext_vector_type(4))) unsigned short ushort4v;

static __device__ __forceinline__ float b2f(unsigned short u) {
  return __builtin_bit_cast(float, ((unsigned int)u) << 16);
}
static __device__ __forceinline__ unsigned short f2b(float f) {
  unsigned int u = __builtin_bit_cast(unsigned int, f);
  u = (u + 0x7fff + ((u >> 16) & 1)) >> 16;  // round-nearest-even
  return (unsigned short)u;
}
// XOR swizzle: element index within a 64-elem (128B) bf16 row
static __device__ __forceinline__ int swz(int row, int d) {
  return d ^ ((row & 7) << 3);
}

#define GLOAD_LDS16(g, l)                                              \
  __builtin_amdgcn_global_load_lds(                                    \
      (const __attribute__((address_space(1))) unsigned int*)(g),      \
      (__attribute__((address_space(3))) unsigned int*)(l), 16, 0, 0)

// ---------------------------------------------------------------------------
// prep: hs fp32->bf16 (blocks 0..2047) + weight transpose (blocks 2048..3071)
// ---------------------------------------------------------------------------
__global__ __launch_bounds__(256) void prep_kernel(
    const float* __restrict__ hs, const float* __restrict__ Wq,
    const float* __restrict__ Wk, const float* __restrict__ Wv,
    const float* __restrict__ Wo, unsigned short* __restrict__ hs_bf,
    unsigned short* __restrict__ WT) {
  __shared__ float t[32][33];
  int bid = blockIdx.x, tid = threadIdx.x;
  if (bid < 2048) {
    int idx = bid * 256 + tid;  // n4 = 524288 = 2048*256 exact
    float4 v = ((const float4*)hs)[idx];
    ushort4v o = {f2b(v.x), f2b(v.y), f2b(v.z), f2b(v.w)};
    *(ushort4v*)(hs_bf + (size_t)idx * 4) = o;
  } else {
    int b2 = bid - 2048;
    int z = b2 >> 8, r = b2 & 255;
    const float* src = (z == 0) ? Wq : (z == 1) ? Wk : (z == 2) ? Wv : Wo;
    int bx = (r & 15) * 32;  // src col block (n)
    int by = (r >> 4) * 32;  // src row block (k)
    int lx = tid & 31, ly = tid >> 5;
#pragma unroll
    for (int i = 0; i < 4; i++)
      t[ly + i * 8][lx] = src[(size_t)(by + ly + i * 8) * 512 + bx + lx];
    __syncthreads();
#pragma unroll
    for (int i = 0; i < 4; i++) {
      int n = bx + ly + i * 8;
      WT[((size_t)z * 512 + n) * 512 + by + lx] = f2b(t[lx][ly + i * 8]);
    }
  }
}

// ---------------------------------------------------------------------------
// MFMA bf16 GEMM, 64x128 tile, BK=32, 4 waves (wave-tile 32x64), 16x16x32.
// MODE 0: A=hs_bf[4096,512], BT=WTcat[1536,512]; bias; elu+1 for q,k.
//   region (bn>>9): 0=q (row-major sqz), 1=k (row-major skz + transposed
//   skTz), 2=v (transposed vTz only). Transposed stores go through a padded
//   LDS buffer -> coalesced 16B stores (chunk swizzle composes to linear).
// MODE 1: A=attnb[4096,512], BT=WoT[512,512]; writes fp32 out.
// ---------------------------------------------------------------------------
template <int MODE>
__global__ __launch_bounds__(256) void mfma_gemm(
    const unsigned short* __restrict__ A, const unsigned short* __restrict__ BT,
    const float* __restrict__ bq, const float* __restrict__ bk,
    const float* __restrict__ bv, unsigned short* __restrict__ sqz,
    unsigned short* __restrict__ skz, unsigned short* __restrict__ skTz,
    unsigned short* __restrict__ vTz, float* __restrict__ outf) {
  union SU {
    struct {
      unsigned short As[64 * 32];   // 4KB
      unsigned short Bs[128 * 32];  // 8KB
    } st;
    unsigned short epsT[128 * 72];  // 18KB, +8 pad per row
  };
  __shared__ SU sh;
  int tid = threadIdx.x;
  int w = tid >> 6, lane = tid & 63;
  int bm = blockIdx.x * 64, bn = blockIdx.y * 128;
  f32x4 acc[2][4] = {};

  int ldrow = lane >> 2;     // 0..15
  int ldk = (lane & 3) * 8;  // 0,8,16,24
  int wr = w >> 1, wc = w & 1;
  int fr = lane & 15, kg8 = (lane >> 4) * 8, q4 = (lane >> 4) * 4;

  for (int k0 = 0; k0 < 512; k0 += 32) {
    // stage: A 4 segs (1/wave), B 8 segs (2/wave)
    GLOAD_LDS16(A + (size_t)(bm + w * 16 + ldrow) * 512 + k0 + ldk,
                sh.st.As + w * 512);
    GLOAD_LDS16(BT + (size_t)(bn + w * 16 + ldrow) * 512 + k0 + ldk,
                sh.st.Bs + w * 512);
    GLOAD_LDS16(BT + (size_t)(bn + (w + 4) * 16 + ldrow) * 512 + k0 + ldk,
                sh.st.Bs + (w + 4) * 512);
    __syncthreads();

    short8 a[2], b[4];
#pragma unroll
    for (int m = 0; m < 2; m++)
      a[m] = *(const short8*)(sh.st.As + (wr * 32 + m * 16 + fr) * 32 + kg8);
#pragma unroll
    for (int n = 0; n < 4; n++)
      b[n] = *(const short8*)(sh.st.Bs + (wc * 64 + n * 16 + fr) * 32 + kg8);
#pragma unroll
    for (int m = 0; m < 2; m++)
#pragma unroll
      for (int n = 0; n < 4; n++)
        acc[m][n] = __builtin_amdgcn_mfma_f32_16x16x32_bf16(a[m], b[n],
                                                            acc[m][n], 0, 0, 0);
    __syncthreads();
  }

  if (MODE == 0) {
    int region = bn >> 9;            // 0=q 1=k 2=v
    int hh_base = (bn & 511) >> 6;   // even
#pragma unroll
    for (int m = 0; m < 2; m++) {
      int sl0 = wr * 32 + m * 16 + q4;
#pragma unroll
      for (int n = 0; n < 4; n++) {
        int cl = wc * 64 + n * 16 + fr;  // 0..127
        int col = bn + cl;
        int m512 = col & 511;
        int hh = m512 >> 6, dd = m512 & 63;
        float bias = (region == 0) ? bq[m512]
                     : (region == 1) ? bk[m512] : bv[m512];
#pragma unroll
        for (int j = 0; j < 4; j++) {
          int sl = sl0 + j;
          int s = bm + sl;
          float val = acc[m][n][j] + bias;
          if (region < 2) val = (val > 0.f) ? (val + 1.f) : __expf(val);
          unsigned short bb = f2b(val);
          if (region == 0) {
            sqz[((size_t)hh * S_LEN + s) * 64 + swz(s, dd)] = bb;
          } else if (region == 1) {
            skz[((size_t)hh * S_LEN + s) * 64 + swz(s, dd)] = bb;
            sh.epsT[cl * 72 + (sl ^ ((cl & 7) << 3))] = bb;
          } else {
            sh.epsT[cl * 72 + (sl ^ ((cl & 7) << 3))] = bb;
          }
        }
      }
    }
    __syncthreads();
    if (region >= 1) {
      unsigned short* Tdst = (region == 1) ? skTz : vTz;
#pragma unroll
      for (int i = 0; i < 4; i++) {
        int G = tid + 256 * i;        // 0..1023
        int gq = G & 7;               // s-granule (16B)
        int cl = G >> 3;              // 0..127
        int hh = hh_base + (cl >> 6), dd = cl & 63;
        short8 v8 = *(const short8*)(sh.epsT + cl * 72 + gq * 8);
        *(short8*)(Tdst + ((size_t)(hh * 64 + dd)) * S_LEN + bm + gq * 8) = v8;
      }
    }
  } else {
#pragma unroll
    for (int m = 0; m < 2; m++) {
      int sl0 = wr * 32 + m * 16 + q4;
#pragma unroll
      for (int n = 0; n < 4; n++) {
        int col = bn + wc * 64 + n * 16 + fr;
#pragma unroll
        for (int j = 0; j < 4; j++)
          outf[(size_t)(bm + sl0 + j) * 512 + col] = acc[m][n][j];
      }
    }
  }
}

// ---------------------------------------------------------------------------
// Per-(head,chunk) MFMA: KVt[e][d] = sum_t v[t][e]*sk[t][d]  (A=vT, BT=skT)
// ones-row trick (A row 64 = 1) gives ksum[d] = sum_t sk[t][d] in C row 64.
// ---------------------------------------------------------------------------
__global__ __launch_bounds__(256) void chunk_sum_mfma(
    const unsigned short* __restrict__ vTz, const unsigned short* __restrict__ skTz,
    float* __restrict__ KVt, float* __restrict__ ksum) {
  __shared__ unsigned short vt_lds[64 * 64];
  __shared__ unsigned short skt_lds[64 * 64];
  int h = blockIdx.x / NC, c = blockIdx.x % NC;
  int tid = threadIdx.x, w = tid >> 6, lane = tid & 63;
  int lr = lane >> 3, lc = (lane & 7) * 8;
#pragma unroll
  for (int i = 0; i < 2; i++) {
    int seg = w * 2 + i;
    GLOAD_LDS16(vTz + ((size_t)h * 64 + seg * 8 + lr) * S_LEN + c * 64 + lc,
                vt_lds + seg * 512);
    GLOAD_LDS16(skTz + ((size_t)h * 64 + seg * 8 + lr) * S_LEN + c * 64 + lc,
                skt_lds + seg * 512);
  }
  __syncthreads();

  int fr = lane & 15, kg = (lane >> 4) * 8;
  short8 onesA = {};
  if (fr == 0) {
#pragma unroll
    for (int j = 0; j < 8; j++) onesA[j] = (short)0x3F80;
  }
  f32x4 acc[4] = {};
  f32x4 accK[4] = {};
#pragma unroll
  for (int k0 = 0; k0 < 64; k0 += 32) {
    int e = w * 16 + fr;
    short8 a = *(const short8*)(vt_lds + e * 64 + ((k0 + kg) ^ ((e & 7) << 3)));
    short8 b[4];
#pragma unroll
    for (int nt = 0; nt < 4; nt++) {
      int d = nt * 16 + fr;
      b[nt] = *(const short8*)(skt_lds + d * 64 + ((k0 + kg) ^ ((d & 7) << 3)));
    }
#pragma unroll
    for (int nt = 0; nt < 4; nt++)
      acc[nt] = __builtin_amdgcn_mfma_f32_16x16x32_bf16(a, b[nt], acc[nt], 0, 0, 0);
    if (w == 0) {
#pragma unroll
      for (int nt = 0; nt < 4; nt++)
        accK[nt] =
            __builtin_amdgcn_mfma_f32_16x16x32_bf16(onesA, b[nt], accK[nt], 0, 0, 0);
    }
  }
  int e0 = w * 16 + (lane >> 4) * 4;
  size_t base = (size_t)(h * NC + c) * 4096;
#pragma unroll
  for (int nt = 0; nt < 4; nt++)
#pragma unroll
    for (int j = 0; j < 4; j++)
      KVt[base + (size_t)(e0 + j) * 64 + nt * 16 + fr] = acc[nt][j];
  if (w == 0 && lane < 16) {
#pragma unroll
    for (int nt = 0; nt < 4; nt++)
      ksum[(size_t)(h * NC + c) * 64 + nt * 16 + lane] = accK[nt][0];
  }
}

// ---------------------------------------------------------------------------
// Exclusive prefix over chunks (seeded by M_mem/z_mem), emitted as swizzled
// bf16 KVpz[h][c][e][swz(e,d)] and zp_bf[h][c][d].
// ---------------------------------------------------------------------------
__global__ __launch_bounds__(256) void prefix_kernel(
    const float* __restrict__ KVt, const float* __restrict__ ksum,
    const float* __restrict__ M_mem, const float* __restrict__ z_mem,
    unsigned short* __restrict__ KVpz, unsigned short* __restrict__ zp_bf) {
  int h = blockIdx.x >> 4, g = blockIdx.x & 15;
  int tid = threadIdx.x;
  int entry = g * 256 + tid, e = entry >> 6, d = entry & 63;
  float pref = M_mem[h * 4096 + d * 64 + e];  // M_mem[h][d][e] seeds KVt[e][d]
  size_t i0 = (size_t)(h * NC) * 4096 + (size_t)e * 64 + d;
  size_t o0 = (size_t)(h * NC) * 4096 + (size_t)e * 64 + swz(e, d);
  for (int c = 0; c < NC; c += 4) {
    float v0 = KVt[i0 + (size_t)c * 4096];
    float v1 = KVt[i0 + (size_t)(c + 1) * 4096];
    float v2 = KVt[i0 + (size_t)(c + 2) * 4096];
    float v3 = KVt[i0 + (size_t)(c + 3) * 4096];
    KVpz[o0 + (size_t)c * 4096] = f2b(pref);
    pref += v0;
    KVpz[o0 + (size_t)(c + 1) * 4096] = f2b(pref);
    pref += v1;
    KVpz[o0 + (size_t)(c + 2) * 4096] = f2b(pref);
    pref += v2;
    KVpz[o0 + (size_t)(c + 3) * 4096] = f2b(pref);
    pref += v3;
  }
  if (g == 0 && tid < 64) {
    float zp = z_mem[h * 64 + tid];
    for (int c = 0; c < NC; c += 4) {
      float u0 = ksum[(size_t)(h * NC + c) * 64 + tid];
      float u1 = ksum[(size_t)(h * NC + c + 1) * 64 + tid];
      float u2 = ksum[(size_t)(h * NC + c + 2) * 64 + tid];
      float u3 = ksum[(size_t)(h * NC + c + 3) * 64 + tid];
      zp_bf[(size_t)(h * NC + c) * 64 + tid] = f2b(zp);
      zp += u0;
      zp_bf[(size_t)(h * NC + c + 1) * 64 + tid] = f2b(zp);
      zp += u1;
      zp_bf[(size_t)(h * NC + c + 2) * 64 + tid] = f2b(zp);
      zp += u2;
      zp_bf[(size_t)(h * NC + c + 3) * 64 + tid] = f2b(zp);
      zp += u3;
    }
  }
}

// ---------------------------------------------------------------------------
// Per-(head,chunk) attention, all-MFMA.
// Stage 1: S = sq @ sk^T (64x64x64), causal-masked, split hi/lo bf16.
// Stage 2: [Shi|Slo|sq](64x192) @ [v|v|Mp](192x80) -> num (cols 0..63),
//          den (col 64 via ones/zp column). out = num/(den+eps) -> attnb bf16.
// ---------------------------------------------------------------------------
__global__ __launch_bounds__(256) void attn_mfma(
    const unsigned short* __restrict__ sqz, const unsigned short* __restrict__ skz,
    const unsigned short* __restrict__ vTz, const unsigned short* __restrict__ KVpz,
    const unsigned short* __restrict__ zp_bf, unsigned short* __restrict__ attnb) {
  __shared__ unsigned short sq_lds[4096], sk_lds[4096];
  __shared__ unsigned short btv_lds[80 * 64], btm_lds[80 * 64];
  __shared__ unsigned short shi_lds[4096], slo_lds[4096];
  int h = blockIdx.x / NC, c = blockIdx.x % NC;
  int tid = threadIdx.x, w = tid >> 6, lane = tid & 63;

  {
    const unsigned short* sq_g = sqz + ((size_t)h * S_LEN + c * 64) * 64;
    const unsigned short* sk_g = skz + ((size_t)h * S_LEN + c * 64) * 64;
    const unsigned short* km_g = KVpz + (size_t)(h * NC + c) * 4096;
    int lr = lane >> 3, lc = (lane & 7) * 8;
#pragma unroll
    for (int i = 0; i < 2; i++) {
      int seg = w * 2 + i;
      GLOAD_LDS16(sq_g + seg * 512 + lane * 8, sq_lds + seg * 512);
      GLOAD_LDS16(sk_g + seg * 512 + lane * 8, sk_lds + seg * 512);
      GLOAD_LDS16(km_g + seg * 512 + lane * 8, btm_lds + seg * 512);
      GLOAD_LDS16(vTz + ((size_t)h * 64 + seg * 8 + lr) * S_LEN + c * 64 + lc,
                  btv_lds + seg * 512);
    }
  }
  if (tid < 8) {  // row 64: ones column (den intra) and zp column (den inter)
    short8 one;
#pragma unroll
    for (int j = 0; j < 8; j++) one[j] = (short)0x3F80;
    *(short8*)(btv_lds + 64 * 64 + tid * 8) = one;
    *(short8*)(btm_lds + 64 * 64 + tid * 8) =
        *(const short8*)(zp_bf + (size_t)(h * NC + c) * 64 + tid * 8);
  }
  __syncthreads();

  int fr = lane & 15, kg8 = (lane >> 4) * 8;
  int ta = w * 16 + fr;              // a-frag row
  int sw_a = (ta & 7) << 3;

  // ---- stage 1: S = sq @ sk^T ----
  f32x4 accS[4] = {};
#pragma unroll
  for (int k0 = 0; k0 < 64; k0 += 32) {
    short8 a = *(const short8*)(sq_lds + ta * 64 + ((k0 + kg8) ^ sw_a));
#pragma unroll
    for (int nt = 0; nt < 4; nt++) {
      int tp = nt * 16 + fr;
      short8 b = *(const short8*)(sk_lds + tp * 64 + ((k0 + kg8) ^ ((tp & 7) << 3)));
      accS[nt] = __builtin_amdgcn_mfma_f32_16x16x32_bf16(a, b, accS[nt], 0, 0, 0);
    }
  }
  // ---- mask + hi/lo split, write to LDS (own rows only -> no barrier) ----
  int r0 = (lane >> 4) * 4;
#pragma unroll
  for (int nt = 0; nt < 4; nt++) {
    int tp = nt * 16 + fr;
#pragma unroll
    for (int j = 0; j < 4; j++) {
      int t = w * 16 + r0 + j;
      float s = (tp <= t) ? accS[nt][j] : 0.f;
      unsigned short hi = f2b(s);
      unsigned short lo = f2b(s - b2f(hi));
      shi_lds[t * 64 + swz(t, tp)] = hi;
      slo_lds[t * 64 + swz(t, tp)] = lo;
    }
  }
  // ---- stage 2: [Shi|Slo|sq] @ [v|v|Mp] ----
  f32x4 acc2[5] = {};
#pragma unroll
  for (int ks = 0; ks < 6; ks++) {
    const unsigned short* asrc = (ks < 2) ? shi_lds : (ks < 4) ? slo_lds : sq_lds;
    const unsigned short* bsrc = (ks < 4) ? btv_lds : btm_lds;
    int ak = (ks & 1) * 32 + kg8;
    short8 a = *(const short8*)(asrc + ta * 64 + (ak ^ sw_a));
#pragma unroll
    for (int nt = 0; nt < 5; nt++) {
      int n = nt * 16 + fr;
      short8 b = *(const short8*)(bsrc + n * 64 + (ak ^ ((n & 7) << 3)));
      acc2[nt] = __builtin_amdgcn_mfma_f32_16x16x32_bf16(a, b, acc2[nt], 0, 0, 0);
    }
  }
  // ---- den broadcast + write ----
  float inv[4];
#pragma unroll
  for (int j = 0; j < 4; j++) {
    float dj = __shfl(acc2[4][j], (lane & 48), 64);
    inv[j] = 1.f / (dj + EPS);
  }
  int srow = c * 64 + w * 16 + r0;
#pragma unroll
  for (int nt = 0; nt < 4; nt++) {
    int col = h * 64 + nt * 16 + fr;
#pragma unroll
    for (int j = 0; j < 4; j++)
      attnb[(size_t)(srow + j) * 512 + col] = f2b(acc2[nt][j] * inv[j]);
  }
}

// ---------------------------------------------------------------------------
extern "C" void kernel_launch(void* const* d_in, const int* in_sizes, int n_in,
                              void* d_out, int out_size, void* d_ws,
                              size_t ws_size, hipStream_t stream) {
  const float* hs = (const float*)d_in[0];
  const float* Wq = (const float*)d_in[1];
  const float* bq = (const float*)d_in[2];
  const float* Wk = (const float*)d_in[3];
  const float* bk = (const float*)d_in[4];
  const float* Wv = (const float*)d_in[5];
  const float* bv = (const float*)d_in[6];
  const float* Wo = (const float*)d_in[7];
  const float* M_mem = (const float*)d_in[8];
  const float* z_mem = (const float*)d_in[9];
  float* out = (float*)d_out;

  unsigned short* hs_bf = (unsigned short*)d_ws;           // 2M sh
  unsigned short* WT = hs_bf + (size_t)S_LEN * D_HID;      // 1M sh
  unsigned short* sqz = WT + (size_t)4 * 512 * 512;        // 2M sh
  unsigned short* skz = sqz + (size_t)H_NUM * S_LEN * DH;  // 2M sh
  unsigned short* skTz = skz + (size_t)H_NUM * S_LEN * DH; // 2M sh
  unsigned short* vTz = skTz + (size_t)H_NUM * S_LEN * DH; // 2M sh
  unsigned short* attnb = vTz + (size_t)H_NUM * S_LEN * DH;       // 2M sh
  unsigned short* KVpz = attnb + (size_t)S_LEN * P_DIM;           // 2M sh
  unsigned short* zp_bf = KVpz + (size_t)H_NUM * NC * DH * DH;    // 32K sh
  float* KVt = (float*)(zp_bf + (size_t)H_NUM * NC * DH);         // 2M f
  float* ksum = KVt + (size_t)H_NUM * NC * DH * DH;               // 32K f

  prep_kernel<<<3072, 256, 0, stream>>>(hs, Wq, Wk, Wv, Wo, hs_bf, WT);

  dim3 pg(S_LEN / 64, 1536 / 128);
  mfma_gemm<0><<<pg, 256, 0, stream>>>(hs_bf, WT, bq, bk, bv, sqz, skz, skTz,
                                       vTz, nullptr);

  chunk_sum_mfma<<<H_NUM * NC, 256, 0, stream>>>(vTz, skTz, KVt, ksum);
  prefix_kernel<<<H_NUM * 16, 256, 0, stream>>>(KVt, ksum, M_mem, z_mem, KVpz,
                                                zp_bf);
  attn_mfma<<<H_NUM * NC, 256, 0, stream>>>(sqz, skz, vTz, KVpz, zp_bf, attnb);

  dim3 og(S_LEN / 64, 512 / 128);
  mfma_gemm<1><<<og, 256, 0, stream>>>(attnb, WT + (size_t)3 * 512 * 512,
                                       nullptr, nullptr, nullptr, nullptr,
                                       nullptr, nullptr, nullptr, out);
}

// Round 8
// 121.076 us; speedup vs baseline: 3.1881x; 1.0412x over previous
//
#include <hip/hip_runtime.h>
#include <hip/hip_bf16.h>
#include <math.h>

// Problem constants (fixed by setup_inputs)
#define S_LEN 4096
#define D_HID 512
#define P_DIM 512
#define H_NUM 8
#define DH 64
#define NC 64          // chunks per head (chunk = 64 rows)
#define EPS 1e-6f

typedef __attribute__((ext_vector_type(8))) short short8;
typedef __attribute__((ext_vector_type(4))) float f32x4;
typedef __attribute__((ext_vector_type(4))) unsigned short ushort4v;

static __device__ __forceinline__ float b2f(unsigned short u) {
  return __builtin_bit_cast(float, ((unsigned int)u) << 16);
}
static __device__ __forceinline__ unsigned short f2b(float f) {
  unsigned int u = __builtin_bit_cast(unsigned int, f);
  u = (u + 0x7fff + ((u >> 16) & 1)) >> 16;  // round-nearest-even
  return (unsigned short)u;
}
// XOR swizzle: element index within a 64-elem (128B) bf16 row
static __device__ __forceinline__ int swz(int row, int d) {
  return d ^ ((row & 7) << 3);
}

#define GLOAD_LDS16(g, l)                                              \
  __builtin_amdgcn_global_load_lds(                                    \
      (const __attribute__((address_space(1))) unsigned int*)(g),      \
      (__attribute__((address_space(3))) unsigned int*)(l), 16, 0, 0)

#define MFMA16(a, b, c) __builtin_amdgcn_mfma_f32_16x16x32_bf16(a, b, c, 0, 0, 0)

#define VMCNT0 asm volatile("s_waitcnt vmcnt(0)" ::: "memory")

// ---------------------------------------------------------------------------
// prep: hs fp32->bf16 (blocks 0..2047) + weight transpose (blocks 2048..3071)
// ---------------------------------------------------------------------------
__global__ __launch_bounds__(256) void prep_kernel(
    const float* __restrict__ hs, const float* __restrict__ Wq,
    const float* __restrict__ Wk, const float* __restrict__ Wv,
    const float* __restrict__ Wo, unsigned short* __restrict__ hs_bf,
    unsigned short* __restrict__ WT) {
  __shared__ float t[32][33];
  int bid = blockIdx.x, tid = threadIdx.x;
  if (bid < 2048) {
    int idx = bid * 256 + tid;  // n4 = 524288 = 2048*256 exact
    float4 v = ((const float4*)hs)[idx];
    ushort4v o = {f2b(v.x), f2b(v.y), f2b(v.z), f2b(v.w)};
    *(ushort4v*)(hs_bf + (size_t)idx * 4) = o;
  } else {
    int b2 = bid - 2048;
    int z = b2 >> 8, r = b2 & 255;
    const float* src = (z == 0) ? Wq : (z == 1) ? Wk : (z == 2) ? Wv : Wo;
    int bx = (r & 15) * 32;  // src col block (n)
    int by = (r >> 4) * 32;  // src row block (k)
    int lx = tid & 31, ly = tid >> 5;
#pragma unroll
    for (int i = 0; i < 4; i++)
      t[ly + i * 8][lx] = src[(size_t)(by + ly + i * 8) * 512 + bx + lx];
    __syncthreads();
#pragma unroll
    for (int i = 0; i < 4; i++) {
      int n = bx + ly + i * 8;
      WT[((size_t)z * 512 + n) * 512 + by + lx] = f2b(t[lx][ly + i * 8]);
    }
  }
}

// ---------------------------------------------------------------------------
// proj: per-(chunk c = blockIdx.x, head h = blockIdx.y) 64x192 GEMM
// (q|k|v for this head's 64 cols each), K=512, BK=32, 2-phase dbuf staging,
// 4 waves each owning 16 M-rows x 192 N-cols (12 MFMA/K-step).
// Epilogue: bias+act -> sqz/skz global (swizzled row-major) + skT/vT in LDS;
// then vT -> vTz global (coalesced) and chunk-sum MFMA -> KVt fp32 + ksum
// (ones-A-row trick).
// ---------------------------------------------------------------------------
__global__ __launch_bounds__(256) void proj_kernel(
    const unsigned short* __restrict__ hs_bf,
    const unsigned short* __restrict__ WT, const float* __restrict__ bq,
    const float* __restrict__ bk, const float* __restrict__ bv,
    unsigned short* __restrict__ sqz, unsigned short* __restrict__ skz,
    unsigned short* __restrict__ vTz, float* __restrict__ KVt,
    float* __restrict__ ksum) {
  union U {
    struct {
      unsigned short As[2][64 * 32];   // 2x4KB
      unsigned short Bs[2][192 * 32];  // 2x12KB
    } st;
    struct {
      unsigned short skT[64 * 64];  // 8KB
      unsigned short vT[64 * 64];   // 8KB
    } cs;
  };
  __shared__ U u;
  int tid = threadIdx.x, w = tid >> 6, lane = tid & 63;
  int c = blockIdx.x, h = blockIdx.y;
  int fr = lane & 15, kg8 = (lane >> 4) * 8, q4 = (lane >> 4) * 4;
  int ldrow = lane >> 2, ldk = (lane & 3) * 8;

  const unsigned short* Ag =
      hs_bf + (size_t)(c * 64 + w * 16 + ldrow) * 512 + ldk;
  const unsigned short* Bg =
      WT + (size_t)(h * 64 + w * 16 + ldrow) * 512 + ldk;

#define PSTAGE(buf, k0)                                              \
  do {                                                               \
    GLOAD_LDS16(Ag + (k0), u.st.As[buf] + w * 512);                  \
    GLOAD_LDS16(Bg + (k0), u.st.Bs[buf] + w * 512);                  \
    GLOAD_LDS16(Bg + 262144 + (k0), u.st.Bs[buf] + 2048 + w * 512);  \
    GLOAD_LDS16(Bg + 524288 + (k0), u.st.Bs[buf] + 4096 + w * 512);  \
  } while (0)

  f32x4 acc[12] = {};
  PSTAGE(0, 0);
  VMCNT0;
  __builtin_amdgcn_s_barrier();
  int cur = 0;
  for (int it = 0; it < 16; it++) {
    if (it < 15) PSTAGE(cur ^ 1, (it + 1) * 32);
    short8 a = *(const short8*)(u.st.As[cur] + (w * 16 + fr) * 32 + kg8);
#pragma unroll
    for (int nt = 0; nt < 12; nt++) {
      short8 b = *(const short8*)(u.st.Bs[cur] + (nt * 16 + fr) * 32 + kg8);
      acc[nt] = MFMA16(a, b, acc[nt]);
    }
    VMCNT0;
    __builtin_amdgcn_s_barrier();
    cur ^= 1;
  }

  // epilogue: bias + activation -> global sq/sk + LDS skT/vT
#pragma unroll
  for (int nt = 0; nt < 12; nt++) {
    int z = nt >> 2, d = (nt & 3) * 16 + fr;
    float bias = (z == 0) ? bq[h * 64 + d]
                          : (z == 1) ? bk[h * 64 + d] : bv[h * 64 + d];
#pragma unroll
    for (int j = 0; j < 4; j++) {
      int t = w * 16 + q4 + j;
      int s = c * 64 + t;
      float val = acc[nt][j] + bias;
      if (z < 2) val = (val > 0.f) ? (val + 1.f) : __expf(val);
      unsigned short bb = f2b(val);
      if (z == 0) {
        sqz[((size_t)h * S_LEN + s) * 64 + swz(s, d)] = bb;
      } else if (z == 1) {
        skz[((size_t)h * S_LEN + s) * 64 + swz(s, d)] = bb;
        u.cs.skT[d * 64 + swz(d, t)] = bb;
      } else {
        u.cs.vT[d * 64 + swz(d, t)] = bb;
      }
    }
  }
  __syncthreads();

  // vT -> vTz (coalesced 16B rows; swizzle already applied in LDS layout)
#pragma unroll
  for (int i = 0; i < 2; i++) {
    int G = tid + 256 * i;  // 0..511
    int e = G >> 3, gq = G & 7;
    *(short8*)(vTz + ((size_t)(h * 64 + e)) * S_LEN + c * 64 + gq * 8) =
        *(const short8*)(u.cs.vT + e * 64 + gq * 8);
  }

  // chunk-sum MFMA: KVt[e][d] = sum_t v[t][e]*sk[t][d]; ksum via ones-A row 0
  {
    short8 onesA = {};
    if (fr == 0) {
#pragma unroll
      for (int j = 0; j < 8; j++) onesA[j] = (short)0x3F80;
    }
    f32x4 accC[4] = {}, accKk[4] = {};
#pragma unroll
    for (int k0 = 0; k0 < 64; k0 += 32) {
      int e = w * 16 + fr;
      short8 a2 =
          *(const short8*)(u.cs.vT + e * 64 + ((k0 + kg8) ^ ((e & 7) << 3)));
#pragma unroll
      for (int nt = 0; nt < 4; nt++) {
        int d = nt * 16 + fr;
        short8 b2 = *(const short8*)(u.cs.skT + d * 64 +
                                     ((k0 + kg8) ^ ((d & 7) << 3)));
        accC[nt] = MFMA16(a2, b2, accC[nt]);
        if (w == 0) accKk[nt] = MFMA16(onesA, b2, accKk[nt]);
      }
    }
    size_t base = (size_t)(h * NC + c) * 4096;
    int e0 = w * 16 + q4;
#pragma unroll
    for (int nt = 0; nt < 4; nt++)
#pragma unroll
      for (int j = 0; j < 4; j++)
        KVt[base + (size_t)(e0 + j) * 64 + nt * 16 + fr] = accC[nt][j];
    if (w == 0 && lane < 16) {
#pragma unroll
      for (int nt = 0; nt < 4; nt++)
        ksum[(size_t)(h * NC + c) * 64 + nt * 16 + lane] = accKk[nt][0];
    }
  }
#undef PSTAGE
}

// ---------------------------------------------------------------------------
// Parallel exclusive prefix over chunks (512 blocks: head = bid>>6, e-row =
// bid&63; 4-way chunk split per block), seeded M_mem/z_mem; emits swizzled
// bf16 KVpz[h][c][e][swz(e,d)] and zp_bf[h][c][d].
// ---------------------------------------------------------------------------
__global__ __launch_bounds__(256) void prefix2_kernel(
    const float* __restrict__ KVt, const float* __restrict__ ksum,
    const float* __restrict__ M_mem, const float* __restrict__ z_mem,
    unsigned short* __restrict__ KVpz, unsigned short* __restrict__ zp_bf) {
  __shared__ float p[64 * 4];
  __shared__ float zz[64 * 4];
  int h = blockIdx.x >> 6, seg = blockIdx.x & 63;  // e-row
  int tid = threadIdx.x;
  int d = tid & 63, q = tid >> 6;  // d entry, chunk-quarter
  size_t ebase = (size_t)h * NC * 4096 + (size_t)seg * 64 + d;
  float part = 0.f;
#pragma unroll 4
  for (int i = 0; i < 16; i++)
    part += KVt[ebase + (size_t)(q * 16 + i) * 4096];
  p[d * 4 + q] = part;
  if (seg == 0) {
    size_t zb = (size_t)h * NC * 64 + d;
    float pz = 0.f;
#pragma unroll 4
    for (int i = 0; i < 16; i++) pz += ksum[zb + (size_t)(q * 16 + i) * 64];
    zz[d * 4 + q] = pz;
  }
  __syncthreads();
  float pref = M_mem[h * 4096 + d * 64 + seg];  // M_mem[h][d][e] seeds [e][d]
  for (int q2 = 0; q2 < q; q2++) pref += p[d * 4 + q2];
  int sw = swz(seg, d);
#pragma unroll 4
  for (int i = 0; i < 16; i++) {
    int cc = q * 16 + i;
    KVpz[(size_t)(h * NC + cc) * 4096 + seg * 64 + sw] = f2b(pref);
    pref += KVt[ebase + (size_t)cc * 4096];
  }
  if (seg == 0) {
    float bz = z_mem[h * 64 + d];
    for (int q2 = 0; q2 < q; q2++) bz += zz[d * 4 + q2];
    size_t zb = (size_t)h * NC * 64 + d;
#pragma unroll 4
    for (int i = 0; i < 16; i++) {
      int cc = q * 16 + i;
      zp_bf[zb + (size_t)cc * 64] = f2b(bz);
      bz += ksum[zb + (size_t)cc * 64];
    }
  }
}

// ---------------------------------------------------------------------------
// Per-(head,chunk) attention, all-MFMA (validated round-5 version).
// Stage 1: S = sq @ sk^T (64x64x64), causal-masked, split hi/lo bf16.
// Stage 2: [Shi|Slo|sq](64x192) @ [v|v|Mp](192x80) -> num (cols 0..63),
//          den (col 64 via ones/zp column). out = num/(den+eps) -> attnb bf16.
// ---------------------------------------------------------------------------
__global__ __launch_bounds__(256) void attn_mfma(
    const unsigned short* __restrict__ sqz, const unsigned short* __restrict__ skz,
    const unsigned short* __restrict__ vTz, const unsigned short* __restrict__ KVpz,
    const unsigned short* __restrict__ zp_bf, unsigned short* __restrict__ attnb) {
  __shared__ unsigned short sq_lds[4096], sk_lds[4096];
  __shared__ unsigned short btv_lds[80 * 64], btm_lds[80 * 64];
  __shared__ unsigned short shi_lds[4096], slo_lds[4096];
  int h = blockIdx.x / NC, c = blockIdx.x % NC;
  int tid = threadIdx.x, w = tid >> 6, lane = tid & 63;

  {
    const unsigned short* sq_g = sqz + ((size_t)h * S_LEN + c * 64) * 64;
    const unsigned short* sk_g = skz + ((size_t)h * S_LEN + c * 64) * 64;
    const unsigned short* km_g = KVpz + (size_t)(h * NC + c) * 4096;
    int lr = lane >> 3, lc = (lane & 7) * 8;
#pragma unroll
    for (int i = 0; i < 2; i++) {
      int seg = w * 2 + i;
      GLOAD_LDS16(sq_g + seg * 512 + lane * 8, sq_lds + seg * 512);
      GLOAD_LDS16(sk_g + seg * 512 + lane * 8, sk_lds + seg * 512);
      GLOAD_LDS16(km_g + seg * 512 + lane * 8, btm_lds + seg * 512);
      GLOAD_LDS16(vTz + ((size_t)h * 64 + seg * 8 + lr) * S_LEN + c * 64 + lc,
                  btv_lds + seg * 512);
    }
  }
  if (tid < 8) {  // row 64: ones column (den intra) and zp column (den inter)
    short8 one;
#pragma unroll
    for (int j = 0; j < 8; j++) one[j] = (short)0x3F80;
    *(short8*)(btv_lds + 64 * 64 + tid * 8) = one;
    *(short8*)(btm_lds + 64 * 64 + tid * 8) =
        *(const short8*)(zp_bf + (size_t)(h * NC + c) * 64 + tid * 8);
  }
  __syncthreads();

  int fr = lane & 15, kg8 = (lane >> 4) * 8;
  int ta = w * 16 + fr;  // a-frag row
  int sw_a = (ta & 7) << 3;

  // ---- stage 1: S = sq @ sk^T ----
  f32x4 accS[4] = {};
#pragma unroll
  for (int k0 = 0; k0 < 64; k0 += 32) {
    short8 a = *(const short8*)(sq_lds + ta * 64 + ((k0 + kg8) ^ sw_a));
#pragma unroll
    for (int nt = 0; nt < 4; nt++) {
      int tp = nt * 16 + fr;
      short8 b =
          *(const short8*)(sk_lds + tp * 64 + ((k0 + kg8) ^ ((tp & 7) << 3)));
      accS[nt] = MFMA16(a, b, accS[nt]);
    }
  }
  // ---- mask + hi/lo split, write to LDS (own rows only -> no barrier) ----
  int r0 = (lane >> 4) * 4;
#pragma unroll
  for (int nt = 0; nt < 4; nt++) {
    int tp = nt * 16 + fr;
#pragma unroll
    for (int j = 0; j < 4; j++) {
      int t = w * 16 + r0 + j;
      float s = (tp <= t) ? accS[nt][j] : 0.f;
      unsigned short hi = f2b(s);
      unsigned short lo = f2b(s - b2f(hi));
      shi_lds[t * 64 + swz(t, tp)] = hi;
      slo_lds[t * 64 + swz(t, tp)] = lo;
    }
  }
  // ---- stage 2: [Shi|Slo|sq] @ [v|v|Mp] ----
  f32x4 acc2[5] = {};
#pragma unroll
  for (int ks = 0; ks < 6; ks++) {
    const unsigned short* asrc = (ks < 2) ? shi_lds : (ks < 4) ? slo_lds : sq_lds;
    const unsigned short* bsrc = (ks < 4) ? btv_lds : btm_lds;
    int ak = (ks & 1) * 32 + kg8;
    short8 a = *(const short8*)(asrc + ta * 64 + (ak ^ sw_a));
#pragma unroll
    for (int nt = 0; nt < 5; nt++) {
      int n = nt * 16 + fr;
      short8 b = *(const short8*)(bsrc + n * 64 + (ak ^ ((n & 7) << 3)));
      acc2[nt] = MFMA16(a, b, acc2[nt]);
    }
  }
  // ---- den broadcast + write ----
  float inv[4];
#pragma unroll
  for (int j = 0; j < 4; j++) {
    float dj = __shfl(acc2[4][j], (lane & 48), 64);
    inv[j] = 1.f / (dj + EPS);
  }
  int srow = c * 64 + w * 16 + r0;
#pragma unroll
  for (int nt = 0; nt < 4; nt++) {
    int col = h * 64 + nt * 16 + fr;
#pragma unroll
    for (int j = 0; j < 4; j++)
      attnb[(size_t)(srow + j) * 512 + col] = f2b(acc2[nt][j] * inv[j]);
  }
}

// ---------------------------------------------------------------------------
// Output GEMM: out = attnb[4096,512] @ Wo, 64x128 tile, BK=32, 4 waves,
// 2-phase dbuf staging.
// ---------------------------------------------------------------------------
__global__ __launch_bounds__(256) void gemm_out(
    const unsigned short* __restrict__ A, const unsigned short* __restrict__ BT,
    float* __restrict__ outf) {
  __shared__ unsigned short As[2][64 * 32];
  __shared__ unsigned short Bs[2][128 * 32];
  int tid = threadIdx.x, w = tid >> 6, lane = tid & 63;
  int bm = blockIdx.x * 64, bn = blockIdx.y * 128;
  f32x4 acc[2][4] = {};
  int ldrow = lane >> 2, ldk = (lane & 3) * 8;
  int wr = w >> 1, wc = w & 1;
  int fr = lane & 15, kg8 = (lane >> 4) * 8, q4 = (lane >> 4) * 4;
  const unsigned short* Ag = A + (size_t)(bm + w * 16 + ldrow) * 512 + ldk;
  const unsigned short* Bg0 = BT + (size_t)(bn + w * 16 + ldrow) * 512 + ldk;
  const unsigned short* Bg1 =
      BT + (size_t)(bn + (w + 4) * 16 + ldrow) * 512 + ldk;

#define OSTAGE(buf, k0)                              \
  do {                                               \
    GLOAD_LDS16(Ag + (k0), As[buf] + w * 512);       \
    GLOAD_LDS16(Bg0 + (k0), Bs[buf] + w * 512);      \
    GLOAD_LDS16(Bg1 + (k0), Bs[buf] + (w + 4) * 512); \
  } while (0)

  OSTAGE(0, 0);
  VMCNT0;
  __builtin_amdgcn_s_barrier();
  int cur = 0;
  for (int it = 0; it < 16; it++) {
    if (it < 15) OSTAGE(cur ^ 1, (it + 1) * 32);
    short8 a[2], b[4];
#pragma unroll
    for (int m = 0; m < 2; m++)
      a[m] = *(const short8*)(As[cur] + (wr * 32 + m * 16 + fr) * 32 + kg8);
#pragma unroll
    for (int n = 0; n < 4; n++)
      b[n] = *(const short8*)(Bs[cur] + (wc * 64 + n * 16 + fr) * 32 + kg8);
#pragma unroll
    for (int m = 0; m < 2; m++)
#pragma unroll
      for (int n = 0; n < 4; n++) acc[m][n] = MFMA16(a[m], b[n], acc[m][n]);
    VMCNT0;
    __builtin_amdgcn_s_barrier();
    cur ^= 1;
  }
#pragma unroll
  for (int m = 0; m < 2; m++) {
    int sl0 = wr * 32 + m * 16 + q4;
#pragma unroll
    for (int n = 0; n < 4; n++) {
      int col = bn + wc * 64 + n * 16 + fr;
#pragma unroll
      for (int j = 0; j < 4; j++)
        outf[(size_t)(bm + sl0 + j) * 512 + col] = acc[m][n][j];
    }
  }
#undef OSTAGE
}

// ---------------------------------------------------------------------------
extern "C" void kernel_launch(void* const* d_in, const int* in_sizes, int n_in,
                              void* d_out, int out_size, void* d_ws,
                              size_t ws_size, hipStream_t stream) {
  const float* hs = (const float*)d_in[0];
  const float* Wq = (const float*)d_in[1];
  const float* bq = (const float*)d_in[2];
  const float* Wk = (const float*)d_in[3];
  const float* bk = (const float*)d_in[4];
  const float* Wv = (const float*)d_in[5];
  const float* bv = (const float*)d_in[6];
  const float* Wo = (const float*)d_in[7];
  const float* M_mem = (const float*)d_in[8];
  const float* z_mem = (const float*)d_in[9];
  float* out = (float*)d_out;

  unsigned short* hs_bf = (unsigned short*)d_ws;            // 2M sh
  unsigned short* WT = hs_bf + (size_t)S_LEN * D_HID;       // 1M sh
  unsigned short* sqz = WT + (size_t)4 * 512 * 512;         // 2M sh
  unsigned short* skz = sqz + (size_t)H_NUM * S_LEN * DH;   // 2M sh
  unsigned short* vTz = skz + (size_t)H_NUM * S_LEN * DH;   // 2M sh
  unsigned short* attnb = vTz + (size_t)H_NUM * S_LEN * DH;     // 2M sh
  unsigned short* KVpz = attnb + (size_t)S_LEN * P_DIM;         // 2M sh
  unsigned short* zp_bf = KVpz + (size_t)H_NUM * NC * DH * DH;  // 32K sh
  float* KVt = (float*)(zp_bf + (size_t)H_NUM * NC * DH);       // 2M f
  float* ksum = KVt + (size_t)H_NUM * NC * DH * DH;             // 32K f

  prep_kernel<<<3072, 256, 0, stream>>>(hs, Wq, Wk, Wv, Wo, hs_bf, WT);

  proj_kernel<<<dim3(NC, H_NUM), 256, 0, stream>>>(hs_bf, WT, bq, bk, bv, sqz,
                                                   skz, vTz, KVt, ksum);

  prefix2_kernel<<<512, 256, 0, stream>>>(KVt, ksum, M_mem, z_mem, KVpz, zp_bf);

  attn_mfma<<<512, 256, 0, stream>>>(sqz, skz, vTz, KVpz, zp_bf, attnb);

  gemm_out<<<dim3(S_LEN / 64, 512 / 128), 256, 0, stream>>>(
      attnb, WT + (size_t)3 * 512 * 512, out);
}